// Round 16
// baseline (1170.755 us; speedup 1.0000x reference)
//
#include <hip/hip_runtime.h>
#include <hip/hip_fp16.h>

typedef _Float16 f16;
typedef _Float16 f16x4 __attribute__((ext_vector_type(4)));
typedef _Float16 f16x8 __attribute__((ext_vector_type(8)));
typedef float f32x4 __attribute__((ext_vector_type(4)));
typedef unsigned u32x2 __attribute__((ext_vector_type(2)));
typedef unsigned u32x4 __attribute__((ext_vector_type(4)));

#define S_LEN 128
#define B_SZ  128
#define VOC   10000
#define VPAD  10240
#define HIDN  512
#define NBLK  64
#define NFLAG 256   // [2 bg][128] per-wave flags

// counted waitcnt + scheduler fence (rule #18)
#define VMCNT(n) do { asm volatile("s_waitcnt vmcnt(" #n ")" ::: "memory"); \
                      __builtin_amdgcn_sched_barrier(0); } while (0)

__device__ __forceinline__ void gload_lds16(const void* g, void* l) {
  __builtin_amdgcn_global_load_lds(
      (const __attribute__((address_space(1))) void*)g,
      (__attribute__((address_space(3))) void*)l, 16, 0, 0);
}

// device-scope (coherence-point) 16B load; consumer must VMCNT before use
__device__ __forceinline__ f16x8 ld16_dev(const f16* p) {
  u32x4 r;
  asm volatile("global_load_dwordx4 %0, %1, off sc1" : "=v"(r) : "v"(p));
  return __builtin_bit_cast(f16x8, r);
}
// write-through device-scope 8B store (one lane-quad of f16)
__device__ __forceinline__ void cstore8(f16* p, f16x4 v) {
  unsigned long long u = __builtin_bit_cast(unsigned long long, v);
  __hip_atomic_store((unsigned long long*)p, u, __ATOMIC_RELAXED, __HIP_MEMORY_SCOPE_AGENT);
}
// device-scope flag store (plain store, no RMW)
__device__ __forceinline__ void stflag_dev(unsigned* p, unsigned v) {
  asm volatile("global_store_dword %0, %1, off sc1" :: "v"(p), "v"(v) : "memory");
}

// tanh via v_exp + v_rcp
__device__ __forceinline__ float fast_tanh(float x) {
  float cx = fminf(8.f, fmaxf(-8.f, x));
  float e = __expf(2.f * cx);
  float d = e + 1.f, r;
  asm("v_rcp_f32 %0, %1" : "=v"(r) : "v"(d));
  return (e - 1.f) * r;
}

// ---- fp32 -> f16 convert, 512 cols, with zero row padding ----
__global__ void convert_pad(const float* __restrict__ src, f16* __restrict__ dst,
                            int rows, int src_stride, int total) {
  int idx = blockIdx.x * 256 + threadIdx.x;
  if (idx >= total) return;
  int r = idx >> 9, c = idx & 511;
  float v = (r < rows) ? src[(size_t)r * src_stride + c] : 0.f;
  dst[idx] = (f16)v;
}

// ---- GEMM: C[M][ldc] = A[*][512] . B[*][512]^T + bias[col]; 256x256 tiles ----
// 512 threads (8 waves: wrow in [0,4) x wcol in [0,2), each wave 64 rows x 128
// cols -> acc[4][8]). Single-buffered BK=32, 32 KB LDS -> 5 blocks/CU (TLP
// hides stage latency — R13/R15 lesson). All fragment math byte-identical to
// the proven R8/R15 kernel (chunk-linear LDS, sp^((row>>1)&3) swizzle,
// swapped-operand MFMA, dwordx4 C-stores); only tile extents widen.
// FLOP/staged-byte 2x R15; A-panel L2/L3 re-reads halved.
template <typename CT>
__global__ __launch_bounds__(512) void gemm_k512(
    const f16* __restrict__ A, const f16* __restrict__ B,
    CT* __restrict__ C, const float* __restrict__ bias,
    int M, int N, int ldc)
{
  __shared__ f16 Asw[256 * 32];   // 16 KB
  __shared__ f16 Bsw[256 * 32];   // 16 KB
  const int tid  = threadIdx.x;
  const int lane = tid & 63, w = tid >> 6;     // w in [0,8)
  const int wrow = w >> 1, wcol = w & 1;
  int nwg  = gridDim.x * gridDim.y;
  int orig = blockIdx.y * gridDim.x + blockIdx.x;
  int cpx  = nwg >> 3;
  int swz  = (orig & 7) * cpx + (orig >> 3);
  const int m0 = (swz / gridDim.x) * 256, n0 = (swz % gridDim.x) * 256;
  const int rsel = lane & 15, ksl = lane >> 4;

  f32x4 acc[4][8] = {};

  for (int kt = 0; kt < 16; ++kt) {
    __syncthreads();   // previous tile's readers done -> safe to overwrite
    // A-tile & B-tile: 1024 16B-chunks each; wave w stages wavechunks {w, w+8}
#pragma unroll
    for (int i = 0; i < 2; ++i) {
      int ac  = i * 8 + w;
      int c   = ac * 64 + lane;
      int row = c >> 2, sp = c & 3;
      int sl  = sp ^ ((row >> 1) & 3);         // source pre-swizzle
      gload_lds16(A + (size_t)(m0 + row) * 512 + kt * 32 + sl * 8,
                  &Asw[ac * 512]);             // wave-uniform base + lane*16
      gload_lds16(B + (size_t)(n0 + row) * 512 + kt * 32 + sl * 8,
                  &Bsw[ac * 512]);
    }
    __syncthreads();   // implicit vmcnt(0) drain -> staged tile visible

    f16x8 af[4], bf[8];
#pragma unroll
    for (int i = 0; i < 4; ++i) {
      int ar = wrow * 64 + i * 16 + rsel;
      af[i] = *(const f16x8*)&Asw[ar * 32 + ((ksl ^ ((ar >> 1) & 3)) * 8)];
    }
#pragma unroll
    for (int j = 0; j < 8; ++j) {
      int br = wcol * 128 + j * 16 + rsel;
      bf[j] = *(const f16x8*)&Bsw[br * 32 + ((ksl ^ ((br >> 1) & 3)) * 8)];
    }
    // swapped operands: acc[i][j] = C[m0+wrow*64+i*16+rsel][n0+wcol*128+j*16+ksl*4 ..+3]
#pragma unroll
    for (int i = 0; i < 4; ++i)
#pragma unroll
      for (int j = 0; j < 8; ++j)
        acc[i][j] = __builtin_amdgcn_mfma_f32_16x16x32_f16(bf[j], af[i], acc[i][j], 0, 0, 0);
  }

#pragma unroll
  for (int i = 0; i < 4; ++i) {
    int row = m0 + wrow * 64 + i * 16 + rsel;
    if (row >= M) continue;
#pragma unroll
    for (int j = 0; j < 8; ++j) {
      int nb = n0 + wcol * 128 + j * 16 + ksl * 4;
      if (nb >= N) continue;        // N % 4 == 0 => whole quad in/out together
      f32x4 v = acc[i][j];
      if (bias) {
        f32x4 bv = *(const f32x4*)(bias + nb);
        v += bv;
      }
      if constexpr (__is_same(CT, float)) {
        *(f32x4*)&C[(size_t)row * ldc + nb] = v;
      } else {
        f16x4 hv;
#pragma unroll
        for (int q = 0; q < 4; ++q) hv[q] = (f16)v[q];
        *(f16x4*)&C[(size_t)row * ldc + nb] = hv;
      }
    }
  }
}

// ---- cooperative recurrence: R13-EXACT (proven; frozen) ----
__global__ __launch_bounds__(256, 1) void rnn_recur(
    const int* __restrict__ tok,    // [128][128]
    const float* __restrict__ W0,   // [512][1024]
    const float* __restrict__ W1,   // [512][1024]
    const float* __restrict__ b1,   // [512]
    const f16* __restrict__ P0h,    // [10000][512]  emb@W0x^T + b0
    f16* __restrict__ h0ring,       // [4][128][512] (slot 3 = initial h0)
    const f16* __restrict__ h1init, // [128][512]
    f16* __restrict__ H1,           // [128][128][512]
    float* __restrict__ outHid,     // [2][128][512] (d_out tail)
    unsigned* __restrict__ flags)   // [2][128] per-wave flags (zeroed each launch)
{
  __shared__ f16 wlds[3][16 * 512];   // W0h^T, W1a^T, W1b^T column slices, XOR-swizzled
  const int tid = threadIdx.x;
  const int lane = tid & 63, w = tid >> 6;
  const int cgI = blockIdx.x & 31, bg = blockIdx.x >> 5;
  const int col0 = cgI * 16;
  const int rowstart = bg * 64 + w * 16;
  const int rsel = lane & 15, ksl = lane >> 4;
  unsigned* gflags = flags + bg * 128;
  const int fidx = cgI * 4 + w;

  for (int it = tid; it < 3 * 16 * 64; it += 256) {
    int s = it >> 10;
    int rem = it & 1023;
    int c = rem >> 6, ks = rem & 63;
    int n = col0 + c;
    const float* srcp;
    if (s == 0)      srcp = W0 + (size_t)n * 1024 + 512 + ks * 8;  // W0h
    else if (s == 1) srcp = W1 + (size_t)n * 1024 + ks * 8;        // W1a
    else             srcp = W1 + (size_t)n * 1024 + 512 + ks * 8;  // W1b
    f16x8 v;
#pragma unroll
    for (int j = 0; j < 8; ++j) v[j] = (f16)srcp[j];
    *(f16x8*)&wlds[s][c * 512 + ((ks ^ (c & 7)) * 8)] = v;
  }
  const f32x4 b1q = *(const f32x4*)(b1 + col0 + ksl * 4);
  __syncthreads();   // weights visible to all waves; after this, waves are autonomous

  const int myrow = rowstart + rsel;          // lane's batch row
  const size_t hrow = (size_t)myrow * HIDN;
  const int colq = col0 + ksl * 4;            // lane's 4 consecutive hidden cols
  const unsigned* fptr = gflags + 2 * lane;   // 64 lanes x 2 = own bg's 128 flags

  f16x8 hf[16];   // h0(p-1) after MAIN(p); h0(p-2) during SHADOW(p)
  f32x4 part1;

  for (int p = 0; p <= S_LEN + 1; ++p) {
    const bool doH0 = (p <= S_LEN - 1);
    const bool doH1 = (p >= 2);

    // ---- SHADOW: part1 = b1 + W1a@h0(p-2) [regs]; gather (pinned) ----
    if (doH1) {
      f32x4 t = b1q;
#pragma unroll
      for (int kt = 0; kt < 16; ++kt) {
        int ks = kt * 4 + ksl;
        f16x8 b = *(const f16x8*)&wlds[1][rsel * 512 + ((ks ^ (rsel & 7)) * 8)];
        t = __builtin_amdgcn_mfma_f32_16x16x32_f16(b, hf[kt], t, 0, 0, 0);
      }
      part1 = t;
    }
    float pa0, pa1, pa2, pa3;
    if (doH0) {
      int t_ = tok[p * B_SZ + myrow];
      f16x4 pv = *(const f16x4*)&P0h[(size_t)t_ * HIDN + colq];
      pa0 = (float)pv[0]; pa1 = (float)pv[1]; pa2 = (float)pv[2]; pa3 = (float)pv[3];
      // pin: force gather completion here so compiler waitcnts stay out of MAIN
      asm volatile("" : "+v"(pa0), "+v"(pa1), "+v"(pa2), "+v"(pa3));
    }

    // ---- WAIT: own bg's 128 wave-flags >= p ----
    if (p >= 1) {
      const unsigned tgt = (unsigned)p;
      for (;;) {
        u32x2 f;
        asm volatile("global_load_dwordx2 %0, %1, off sc1\n\ts_waitcnt vmcnt(0)"
                     : "=v"(f) : "v"(fptr) : "memory");
        int ok = (f[0] >= tgt) & (f[1] >= tgt);
        if (__all(ok)) break;
      }
    }

    // ---- MAIN: issue device-scope loads (hf first: critical path) ----
    if (p <= S_LEN) {
      const f16* src = h0ring + (size_t)((p - 1) & 3) * B_SZ * HIDN;
#pragma unroll
      for (int kt = 0; kt < 16; ++kt)
        hf[kt] = ld16_dev(src + hrow + kt * 32 + ksl * 8);
    }
    f16x8 h1f[16];
    if (doH1) {
      const f16* h1src = (p == 2) ? h1init : H1 + (size_t)(p - 3) * B_SZ * HIDN;
#pragma unroll
      for (int kt = 0; kt < 16; ++kt)
        h1f[kt] = ld16_dev(h1src + hrow + kt * 32 + ksl * 8);
    }

    float v0, v1, v2, v3;           // layer-0 activations
    if (doH0) {
      if (doH1) { VMCNT(16); } else { VMCNT(0); }   // hf (oldest 16) retired
      f32x4 acc0 = {pa0, pa1, pa2, pa3};
#pragma unroll
      for (int kt = 0; kt < 16; ++kt) {
        int ks = kt * 4 + ksl;
        f16x8 b = *(const f16x8*)&wlds[0][rsel * 512 + ((ks ^ (rsel & 7)) * 8)];
        acc0 = __builtin_amdgcn_mfma_f32_16x16x32_f16(b, hf[kt], acc0, 0, 0, 0);
      }
      v0 = fast_tanh(acc0[0]); v1 = fast_tanh(acc0[1]);
      v2 = fast_tanh(acc0[2]); v3 = fast_tanh(acc0[3]);
      f16* dst = h0ring + (size_t)(p & 3) * B_SZ * HIDN;
      f16x4 hv = {(f16)v0, (f16)v1, (f16)v2, (f16)v3};
      cstore8(&dst[hrow + colq], hv);           // exactly 1 store in flight
    }
    if (doH1) {
      if (doH0) { VMCNT(1); } else { VMCNT(0); }
      // vmcnt in-order: <=1 outstanding => all 16 h1f retired; h0 store may fly
      f32x4 acc1 = part1;
#pragma unroll
      for (int kt = 0; kt < 16; ++kt) {
        int ks = kt * 4 + ksl;
        f16x8 b = *(const f16x8*)&wlds[2][rsel * 512 + ((ks ^ (rsel & 7)) * 8)];
        acc1 = __builtin_amdgcn_mfma_f32_16x16x32_f16(b, h1f[kt], acc1, 0, 0, 0);
      }
      float u0 = fast_tanh(acc1[0]), u1 = fast_tanh(acc1[1]);
      float u2 = fast_tanh(acc1[2]), u3 = fast_tanh(acc1[3]);
      f16* h1dst = H1 + (size_t)(p - 2) * B_SZ * HIDN;
      f16x4 hv = {(f16)u0, (f16)u1, (f16)u2, (f16)u3};
      cstore8(&h1dst[hrow + colq], hv);
      if (p == S_LEN + 1) {
        f32x4 fv = {u0, u1, u2, u3};
        *(f32x4*)&outHid[(size_t)(B_SZ * HIDN) + hrow + colq] = fv;
      }
    }
    if (doH0 && p == S_LEN - 1) {   // deferred (rare): keeps the VMCNT(1) count exact
      f32x4 fv = {v0, v1, v2, v3};
      *(f32x4*)&outHid[hrow + colq] = fv;
    }

    // ---- ARRIVE: per-wave drain + own-flag store ----
    if (p <= S_LEN) {
      VMCNT(0);
      if (lane == 0) stflag_dev(gflags + fidx, (unsigned)(p + 1));
    }
  }
}

extern "C" void kernel_launch(void* const* d_in, const int* in_sizes, int n_in,
                              void* d_out, int out_size, void* d_ws, size_t ws_size,
                              hipStream_t stream) {
  (void)in_sizes; (void)n_in; (void)out_size; (void)ws_size;
  const int*   tok    = (const int*)d_in[0];
  const float* hidden = (const float*)d_in[1];
  const float* emb    = (const float*)d_in[2];
  const float* W0     = (const float*)d_in[3];
  const float* b0     = (const float*)d_in[4];
  const float* W1     = (const float*)d_in[5];
  const float* b1     = (const float*)d_in[6];
  const float* Wout   = (const float*)d_in[7];
  const float* bout   = (const float*)d_in[8];

  char* ws = (char*)d_ws;
  size_t off = 0;
  f16* embf16  = (f16*)(ws + off); off += (size_t)VPAD * 512 * 2;
  f16* woutf16 = (f16*)(ws + off); off += (size_t)VPAD * 512 * 2;
  f16* w0xf16  = (f16*)(ws + off); off += (size_t)512 * 512 * 2;
  f16* P0h     = (f16*)(ws + off); off += (size_t)VOC * 512 * 2;
  f16* H1      = (f16*)(ws + off); off += (size_t)S_LEN * B_SZ * 512 * 2;
  f16* h0ring  = (f16*)(ws + off); off += (size_t)4 * B_SZ * 512 * 2;
  f16* h1init  = (f16*)(ws + off); off += (size_t)B_SZ * 512 * 2;
  unsigned* flags = (unsigned*)(ws + off); off += NFLAG * 4;

  float* outHid = (float*)d_out + (size_t)S_LEN * B_SZ * VOC;

  hipMemsetAsync(flags, 0, NFLAG * 4, stream);   // reset flags each launch

  int tot = VPAD * 512;
  convert_pad<<<(tot + 255) / 256, 256, 0, stream>>>(emb,  embf16,  VOC, 512, tot);
  convert_pad<<<(tot + 255) / 256, 256, 0, stream>>>(Wout, woutf16, VOC, 512, tot);
  tot = 512 * 512;
  convert_pad<<<(tot + 255) / 256, 256, 0, stream>>>(W0, w0xf16, 512, 1024, tot);
  tot = B_SZ * 512;
  convert_pad<<<(tot + 255) / 256, 256, 0, stream>>>(hidden, h0ring + (size_t)3 * B_SZ * 512, B_SZ, 512, tot);
  convert_pad<<<(tot + 255) / 256, 256, 0, stream>>>(hidden + (size_t)B_SZ * 512, h1init, B_SZ, 512, tot);

  // P0 = emb @ W0x^T + b0  (f16 out, [10000][512]); 256x256 tiles: 2 x 40 grid
  gemm_k512<f16><<<dim3(2, VPAD / 256), 512, 0, stream>>>(
      embf16, w0xf16, P0h, b0, VOC, 512, 512);

  // recurrence (cooperative for co-residency; bg-local wave-flag sync inside)
  {
    void* args[] = {(void*)&tok, (void*)&W0, (void*)&W1, (void*)&b1, (void*)&P0h,
                    (void*)&h0ring, (void*)&h1init, (void*)&H1, (void*)&outHid, (void*)&flags};
    hipLaunchCooperativeKernel((const void*)rnn_recur, dim3(NBLK), dim3(256), args, 0, stream);
  }

  // logits = H1 @ Wout^T + bout  -> d_out [16384][10000] fp32; 256x256 tiles
  gemm_k512<float><<<dim3(40, 64), 512, 0, stream>>>(
      H1, woutf16, (float*)d_out, bout, S_LEN * B_SZ, VOC, VOC);
}

// Round 17
// 1114.066 us; speedup vs baseline: 1.0509x; 1.0509x over previous
//
#include <hip/hip_runtime.h>
#include <hip/hip_fp16.h>

typedef _Float16 f16;
typedef _Float16 f16x4 __attribute__((ext_vector_type(4)));
typedef _Float16 f16x8 __attribute__((ext_vector_type(8)));
typedef float f32x4 __attribute__((ext_vector_type(4)));
typedef unsigned u32x2 __attribute__((ext_vector_type(2)));
typedef unsigned u32x4 __attribute__((ext_vector_type(4)));

#define S_LEN 128
#define B_SZ  128
#define VOC   10000
#define VPAD  10240
#define HIDN  512
#define NBLK  64
#define NFLAG 256   // [2 bg][128] per-wave flags

// counted waitcnt + scheduler fence (rule #18)
#define VMCNT(n) do { asm volatile("s_waitcnt vmcnt(" #n ")" ::: "memory"); \
                      __builtin_amdgcn_sched_barrier(0); } while (0)

__device__ __forceinline__ void gload_lds16(const void* g, void* l) {
  __builtin_amdgcn_global_load_lds(
      (const __attribute__((address_space(1))) void*)g,
      (__attribute__((address_space(3))) void*)l, 16, 0, 0);
}

// device-scope (coherence-point) 16B load; consumer must VMCNT before use
__device__ __forceinline__ f16x8 ld16_dev(const f16* p) {
  u32x4 r;
  asm volatile("global_load_dwordx4 %0, %1, off sc1" : "=v"(r) : "v"(p));
  return __builtin_bit_cast(f16x8, r);
}
// write-through device-scope 8B store (one lane-quad of f16)
__device__ __forceinline__ void cstore8(f16* p, f16x4 v) {
  unsigned long long u = __builtin_bit_cast(unsigned long long, v);
  __hip_atomic_store((unsigned long long*)p, u, __ATOMIC_RELAXED, __HIP_MEMORY_SCOPE_AGENT);
}
// device-scope flag store (plain store, no RMW)
__device__ __forceinline__ void stflag_dev(unsigned* p, unsigned v) {
  asm volatile("global_store_dword %0, %1, off sc1" :: "v"(p), "v"(v) : "memory");
}

// tanh via v_exp + v_rcp
__device__ __forceinline__ float fast_tanh(float x) {
  float cx = fminf(8.f, fmaxf(-8.f, x));
  float e = __expf(2.f * cx);
  float d = e + 1.f, r;
  asm("v_rcp_f32 %0, %1" : "=v"(r) : "v"(d));
  return (e - 1.f) * r;
}

// ---- fp32 -> f16 convert, 512 cols, with zero row padding ----
__global__ void convert_pad(const float* __restrict__ src, f16* __restrict__ dst,
                            int rows, int src_stride, int total) {
  int idx = blockIdx.x * 256 + threadIdx.x;
  if (idx >= total) return;
  int r = idx >> 9, c = idx & 511;
  float v = (r < rows) ? src[(size_t)r * src_stride + c] : 0.f;
  dst[idx] = (f16)v;
}

// ---- GEMM: C[M][ldc] = A[*][512] . B[*][512]^T + bias[col]; 256x128 tiles ----
// 512 threads (8 waves: wrow in [0,4) x wcol in [0,2)), single-buffered BK=32,
// 24 KB LDS (TLP hides stage latency, the R13 lesson; R16 showed 256x256's
// register pressure crosses the 2-waves/SIMD cliff — 256x128 is the sweet spot).
// All fragment math byte-identical to the proven R8 kernel (chunk-linear LDS,
// sp^((row>>1)&3) swizzle, swapped-operand MFMA, dwordx4 C-stores).
template <typename CT>
__global__ __launch_bounds__(512) void gemm_k512(
    const f16* __restrict__ A, const f16* __restrict__ B,
    CT* __restrict__ C, const float* __restrict__ bias,
    int M, int N, int ldc)
{
  __shared__ f16 Asw[256 * 32];   // 16 KB
  __shared__ f16 Bsw[128 * 32];   //  8 KB
  const int tid  = threadIdx.x;
  const int lane = tid & 63, w = tid >> 6;     // w in [0,8)
  const int wrow = w >> 1, wcol = w & 1;
  int nwg  = gridDim.x * gridDim.y;
  int orig = blockIdx.y * gridDim.x + blockIdx.x;
  int cpx  = nwg >> 3;
  int swz  = (orig & 7) * cpx + (orig >> 3);
  const int m0 = (swz / gridDim.x) * 256, n0 = (swz % gridDim.x) * 128;
  const int rsel = lane & 15, ksl = lane >> 4;

  f32x4 acc[4][4] = {};

  for (int kt = 0; kt < 16; ++kt) {
    __syncthreads();   // previous tile's readers done -> safe to overwrite
    // A-tile: 1024 16B-chunks; wave w stages wavechunks {w, w+8}
#pragma unroll
    for (int i = 0; i < 2; ++i) {
      int ac  = i * 8 + w;
      int c   = ac * 64 + lane;
      int row = c >> 2, sp = c & 3;
      int sl  = sp ^ ((row >> 1) & 3);         // source pre-swizzle
      gload_lds16(A + (size_t)(m0 + row) * 512 + kt * 32 + sl * 8,
                  &Asw[ac * 512]);             // wave-uniform base + lane*16
    }
    // B-tile: 512 chunks; wave w stages wavechunk w
    {
      int c   = w * 64 + lane;
      int row = c >> 2, sp = c & 3;
      int sl  = sp ^ ((row >> 1) & 3);
      gload_lds16(B + (size_t)(n0 + row) * 512 + kt * 32 + sl * 8,
                  &Bsw[w * 512]);
    }
    __syncthreads();   // implicit vmcnt(0) drain -> staged tile visible

    f16x8 af[4], bf[4];
#pragma unroll
    for (int i = 0; i < 4; ++i) {
      int ar = wrow * 64 + i * 16 + rsel;
      af[i] = *(const f16x8*)&Asw[ar * 32 + ((ksl ^ ((ar >> 1) & 3)) * 8)];
      int br = wcol * 64 + i * 16 + rsel;
      bf[i] = *(const f16x8*)&Bsw[br * 32 + ((ksl ^ ((br >> 1) & 3)) * 8)];
    }
    // swapped operands: acc[i][j] = C[m0+wrow*64+i*16+rsel][n0+wcol*64+j*16+ksl*4 ..+3]
#pragma unroll
    for (int i = 0; i < 4; ++i)
#pragma unroll
      for (int j = 0; j < 4; ++j)
        acc[i][j] = __builtin_amdgcn_mfma_f32_16x16x32_f16(bf[j], af[i], acc[i][j], 0, 0, 0);
  }

#pragma unroll
  for (int i = 0; i < 4; ++i) {
    int row = m0 + wrow * 64 + i * 16 + rsel;
    if (row >= M) continue;
#pragma unroll
    for (int j = 0; j < 4; ++j) {
      int nb = n0 + wcol * 64 + j * 16 + ksl * 4;
      if (nb >= N) continue;        // N % 4 == 0 => whole quad in/out together
      f32x4 v = acc[i][j];
      if (bias) {
        f32x4 bv = *(const f32x4*)(bias + nb);
        v += bv;
      }
      if constexpr (__is_same(CT, float)) {
        *(f32x4*)&C[(size_t)row * ldc + nb] = v;
      } else {
        f16x4 hv;
#pragma unroll
        for (int q = 0; q < 4; ++q) hv[q] = (f16)v[q];
        *(f16x4*)&C[(size_t)row * ldc + nb] = hv;
      }
    }
  }
}

// ---- cooperative recurrence: R13-EXACT (proven passing; frozen) ----
// R12 race-free MAIN + batch-group-local flags. Block (cgI,bg) reads/writes
// h0ring & H1 rows in [bg*64,(bg+1)*64) only => each bg's 128 wave-flags form
// an independent barrier.
__global__ __launch_bounds__(256, 1) void rnn_recur(
    const int* __restrict__ tok,    // [128][128]
    const float* __restrict__ W0,   // [512][1024]
    const float* __restrict__ W1,   // [512][1024]
    const float* __restrict__ b1,   // [512]
    const f16* __restrict__ P0h,    // [10000][512]  emb@W0x^T + b0
    f16* __restrict__ h0ring,       // [4][128][512] (slot 3 = initial h0)
    const f16* __restrict__ h1init, // [128][512]
    f16* __restrict__ H1,           // [128][128][512]
    float* __restrict__ outHid,     // [2][128][512] (d_out tail)
    unsigned* __restrict__ flags)   // [2][128] per-wave flags (zeroed each launch)
{
  __shared__ f16 wlds[3][16 * 512];   // W0h^T, W1a^T, W1b^T column slices, XOR-swizzled
  const int tid = threadIdx.x;
  const int lane = tid & 63, w = tid >> 6;
  const int cgI = blockIdx.x & 31, bg = blockIdx.x >> 5;
  const int col0 = cgI * 16;
  const int rowstart = bg * 64 + w * 16;
  const int rsel = lane & 15, ksl = lane >> 4;
  unsigned* gflags = flags + bg * 128;
  const int fidx = cgI * 4 + w;

  for (int it = tid; it < 3 * 16 * 64; it += 256) {
    int s = it >> 10;
    int rem = it & 1023;
    int c = rem >> 6, ks = rem & 63;
    int n = col0 + c;
    const float* srcp;
    if (s == 0)      srcp = W0 + (size_t)n * 1024 + 512 + ks * 8;  // W0h
    else if (s == 1) srcp = W1 + (size_t)n * 1024 + ks * 8;        // W1a
    else             srcp = W1 + (size_t)n * 1024 + 512 + ks * 8;  // W1b
    f16x8 v;
#pragma unroll
    for (int j = 0; j < 8; ++j) v[j] = (f16)srcp[j];
    *(f16x8*)&wlds[s][c * 512 + ((ks ^ (c & 7)) * 8)] = v;
  }
  const f32x4 b1q = *(const f32x4*)(b1 + col0 + ksl * 4);
  __syncthreads();   // weights visible to all waves; after this, waves are autonomous

  const int myrow = rowstart + rsel;          // lane's batch row
  const size_t hrow = (size_t)myrow * HIDN;
  const int colq = col0 + ksl * 4;            // lane's 4 consecutive hidden cols
  const unsigned* fptr = gflags + 2 * lane;   // 64 lanes x 2 = own bg's 128 flags

  f16x8 hf[16];   // h0(p-1) after MAIN(p); h0(p-2) during SHADOW(p)
  f32x4 part1;

  for (int p = 0; p <= S_LEN + 1; ++p) {
    const bool doH0 = (p <= S_LEN - 1);
    const bool doH1 = (p >= 2);

    // ---- SHADOW: part1 = b1 + W1a@h0(p-2) [regs]; gather (pinned) ----
    if (doH1) {
      f32x4 t = b1q;
#pragma unroll
      for (int kt = 0; kt < 16; ++kt) {
        int ks = kt * 4 + ksl;
        f16x8 b = *(const f16x8*)&wlds[1][rsel * 512 + ((ks ^ (rsel & 7)) * 8)];
        t = __builtin_amdgcn_mfma_f32_16x16x32_f16(b, hf[kt], t, 0, 0, 0);
      }
      part1 = t;
    }
    float pa0, pa1, pa2, pa3;
    if (doH0) {
      int t_ = tok[p * B_SZ + myrow];
      f16x4 pv = *(const f16x4*)&P0h[(size_t)t_ * HIDN + colq];
      pa0 = (float)pv[0]; pa1 = (float)pv[1]; pa2 = (float)pv[2]; pa3 = (float)pv[3];
      // pin: force gather completion here so compiler waitcnts stay out of MAIN
      asm volatile("" : "+v"(pa0), "+v"(pa1), "+v"(pa2), "+v"(pa3));
    }

    // ---- WAIT: own bg's 128 wave-flags >= p ----
    if (p >= 1) {
      const unsigned tgt = (unsigned)p;
      for (;;) {
        u32x2 f;
        asm volatile("global_load_dwordx2 %0, %1, off sc1\n\ts_waitcnt vmcnt(0)"
                     : "=v"(f) : "v"(fptr) : "memory");
        int ok = (f[0] >= tgt) & (f[1] >= tgt);
        if (__all(ok)) break;
      }
    }

    // ---- MAIN: issue device-scope loads (hf first: critical path) ----
    if (p <= S_LEN) {
      const f16* src = h0ring + (size_t)((p - 1) & 3) * B_SZ * HIDN;
#pragma unroll
      for (int kt = 0; kt < 16; ++kt)
        hf[kt] = ld16_dev(src + hrow + kt * 32 + ksl * 8);
    }
    f16x8 h1f[16];
    if (doH1) {
      const f16* h1src = (p == 2) ? h1init : H1 + (size_t)(p - 3) * B_SZ * HIDN;
#pragma unroll
      for (int kt = 0; kt < 16; ++kt)
        h1f[kt] = ld16_dev(h1src + hrow + kt * 32 + ksl * 8);
    }

    float v0, v1, v2, v3;           // layer-0 activations
    if (doH0) {
      if (doH1) { VMCNT(16); } else { VMCNT(0); }   // hf (oldest 16) retired
      f32x4 acc0 = {pa0, pa1, pa2, pa3};
#pragma unroll
      for (int kt = 0; kt < 16; ++kt) {
        int ks = kt * 4 + ksl;
        f16x8 b = *(const f16x8*)&wlds[0][rsel * 512 + ((ks ^ (rsel & 7)) * 8)];
        acc0 = __builtin_amdgcn_mfma_f32_16x16x32_f16(b, hf[kt], acc0, 0, 0, 0);
      }
      v0 = fast_tanh(acc0[0]); v1 = fast_tanh(acc0[1]);
      v2 = fast_tanh(acc0[2]); v3 = fast_tanh(acc0[3]);
      f16* dst = h0ring + (size_t)(p & 3) * B_SZ * HIDN;
      f16x4 hv = {(f16)v0, (f16)v1, (f16)v2, (f16)v3};
      cstore8(&dst[hrow + colq], hv);           // exactly 1 store in flight
    }
    if (doH1) {
      if (doH0) { VMCNT(1); } else { VMCNT(0); }
      // vmcnt in-order: <=1 outstanding => all 16 h1f retired; h0 store may fly
      f32x4 acc1 = part1;
#pragma unroll
      for (int kt = 0; kt < 16; ++kt) {
        int ks = kt * 4 + ksl;
        f16x8 b = *(const f16x8*)&wlds[2][rsel * 512 + ((ks ^ (rsel & 7)) * 8)];
        acc1 = __builtin_amdgcn_mfma_f32_16x16x32_f16(b, h1f[kt], acc1, 0, 0, 0);
      }
      float u0 = fast_tanh(acc1[0]), u1 = fast_tanh(acc1[1]);
      float u2 = fast_tanh(acc1[2]), u3 = fast_tanh(acc1[3]);
      f16* h1dst = H1 + (size_t)(p - 2) * B_SZ * HIDN;
      f16x4 hv = {(f16)u0, (f16)u1, (f16)u2, (f16)u3};
      cstore8(&h1dst[hrow + colq], hv);
      if (p == S_LEN + 1) {
        f32x4 fv = {u0, u1, u2, u3};
        *(f32x4*)&outHid[(size_t)(B_SZ * HIDN) + hrow + colq] = fv;
      }
    }
    if (doH0 && p == S_LEN - 1) {   // deferred (rare): keeps the VMCNT(1) count exact
      f32x4 fv = {v0, v1, v2, v3};
      *(f32x4*)&outHid[hrow + colq] = fv;
    }

    // ---- ARRIVE: per-wave drain + own-flag store ----
    if (p <= S_LEN) {
      VMCNT(0);
      if (lane == 0) stflag_dev(gflags + fidx, (unsigned)(p + 1));
    }
  }
}

extern "C" void kernel_launch(void* const* d_in, const int* in_sizes, int n_in,
                              void* d_out, int out_size, void* d_ws, size_t ws_size,
                              hipStream_t stream) {
  (void)in_sizes; (void)n_in; (void)out_size; (void)ws_size;
  const int*   tok    = (const int*)d_in[0];
  const float* hidden = (const float*)d_in[1];
  const float* emb    = (const float*)d_in[2];
  const float* W0     = (const float*)d_in[3];
  const float* b0     = (const float*)d_in[4];
  const float* W1     = (const float*)d_in[5];
  const float* b1     = (const float*)d_in[6];
  const float* Wout   = (const float*)d_in[7];
  const float* bout   = (const float*)d_in[8];

  char* ws = (char*)d_ws;
  size_t off = 0;
  f16* embf16  = (f16*)(ws + off); off += (size_t)VPAD * 512 * 2;
  f16* woutf16 = (f16*)(ws + off); off += (size_t)VPAD * 512 * 2;
  f16* w0xf16  = (f16*)(ws + off); off += (size_t)512 * 512 * 2;
  f16* P0h     = (f16*)(ws + off); off += (size_t)VOC * 512 * 2;
  f16* H1      = (f16*)(ws + off); off += (size_t)S_LEN * B_SZ * 512 * 2;
  f16* h0ring  = (f16*)(ws + off); off += (size_t)4 * B_SZ * 512 * 2;
  f16* h1init  = (f16*)(ws + off); off += (size_t)B_SZ * 512 * 2;
  unsigned* flags = (unsigned*)(ws + off); off += NFLAG * 4;

  float* outHid = (float*)d_out + (size_t)S_LEN * B_SZ * VOC;

  hipMemsetAsync(flags, 0, NFLAG * 4, stream);   // reset flags each launch

  int tot = VPAD * 512;
  convert_pad<<<(tot + 255) / 256, 256, 0, stream>>>(emb,  embf16,  VOC, 512, tot);
  convert_pad<<<(tot + 255) / 256, 256, 0, stream>>>(Wout, woutf16, VOC, 512, tot);
  tot = 512 * 512;
  convert_pad<<<(tot + 255) / 256, 256, 0, stream>>>(W0, w0xf16, 512, 1024, tot);
  tot = B_SZ * 512;
  convert_pad<<<(tot + 255) / 256, 256, 0, stream>>>(hidden, h0ring + (size_t)3 * B_SZ * 512, B_SZ, 512, tot);
  convert_pad<<<(tot + 255) / 256, 256, 0, stream>>>(hidden + (size_t)B_SZ * 512, h1init, B_SZ, 512, tot);

  // P0 = emb @ W0x^T + b0  (f16 out, [10000][512]); 256-row tiles: 40 x 4 grid
  gemm_k512<f16><<<dim3(4, VPAD / 256), 512, 0, stream>>>(
      embf16, w0xf16, P0h, b0, VOC, 512, 512);

  // recurrence (cooperative for co-residency; bg-local wave-flag sync inside)
  {
    void* args[] = {(void*)&tok, (void*)&W0, (void*)&W1, (void*)&b1, (void*)&P0h,
                    (void*)&h0ring, (void*)&h1init, (void*)&H1, (void*)&outHid, (void*)&flags};
    hipLaunchCooperativeKernel((const void*)rnn_recur, dim3(NBLK), dim3(256), args, 0, stream);
  }

  // logits = H1 @ Wout^T + bout  -> d_out [16384][10000] fp32; 256x128 tiles
  gemm_k512<float><<<dim3(79, 64), 512, 0, stream>>>(
      H1, woutf16, (float*)d_out, bout, S_LEN * B_SZ, VOC, VOC);
}

// Round 18
// 1103.667 us; speedup vs baseline: 1.0608x; 1.0094x over previous
//
#include <hip/hip_runtime.h>
#include <hip/hip_fp16.h>

typedef _Float16 f16;
typedef _Float16 f16x4 __attribute__((ext_vector_type(4)));
typedef _Float16 f16x8 __attribute__((ext_vector_type(8)));
typedef float f32x4 __attribute__((ext_vector_type(4)));
typedef unsigned u32x2 __attribute__((ext_vector_type(2)));
typedef unsigned u32x4 __attribute__((ext_vector_type(4)));

#define S_LEN 128
#define B_SZ  128
#define VOC   10000
#define VPAD  10240
#define HIDN  512
#define NBLK  64
#define NFLAG 256   // [2 bg][128] per-wave flags

// fused-convert segment boundaries (element indices)
#define S0E 5242880    // emb    -> embf16   [VPAD][512], zero row pad
#define S1E 10485760   // Wout   -> woutf16  [VPAD][512], zero row pad
#define S2E 10747904   // W0[:, :512] -> w0xf16 [512][512]
#define S3E 10813440   // hidden[0] -> h0ring slot 3 [128][512]
#define S4E 10878976   // hidden[1] -> h1init        [128][512]

// counted waitcnt + scheduler fence (rule #18)
#define VMCNT(n) do { asm volatile("s_waitcnt vmcnt(" #n ")" ::: "memory"); \
                      __builtin_amdgcn_sched_barrier(0); } while (0)

__device__ __forceinline__ void gload_lds16(const void* g, void* l) {
  __builtin_amdgcn_global_load_lds(
      (const __attribute__((address_space(1))) void*)g,
      (__attribute__((address_space(3))) void*)l, 16, 0, 0);
}

// device-scope (coherence-point) 16B load; consumer must VMCNT before use
__device__ __forceinline__ f16x8 ld16_dev(const f16* p) {
  u32x4 r;
  asm volatile("global_load_dwordx4 %0, %1, off sc1" : "=v"(r) : "v"(p));
  return __builtin_bit_cast(f16x8, r);
}
// write-through device-scope 8B store (one lane-quad of f16)
__device__ __forceinline__ void cstore8(f16* p, f16x4 v) {
  unsigned long long u = __builtin_bit_cast(unsigned long long, v);
  __hip_atomic_store((unsigned long long*)p, u, __ATOMIC_RELAXED, __HIP_MEMORY_SCOPE_AGENT);
}
// device-scope flag store (plain store, no RMW)
__device__ __forceinline__ void stflag_dev(unsigned* p, unsigned v) {
  asm volatile("global_store_dword %0, %1, off sc1" :: "v"(p), "v"(v) : "memory");
}

// tanh via v_exp + v_rcp
__device__ __forceinline__ float fast_tanh(float x) {
  float cx = fminf(8.f, fmaxf(-8.f, x));
  float e = __expf(2.f * cx);
  float d = e + 1.f, r;
  asm("v_rcp_f32 %0, %1" : "=v"(r) : "v"(d));
  return (e - 1.f) * r;
}

// ---- fused fp32->f16 converts: all 5 staging jobs in one grid-stride kernel ----
__global__ __launch_bounds__(256) void convert_all(
    const float* __restrict__ emb, const float* __restrict__ Wout,
    const float* __restrict__ W0, const float* __restrict__ hidden,
    f16* __restrict__ embf16, f16* __restrict__ woutf16,
    f16* __restrict__ w0xf16, f16* __restrict__ h0init, f16* __restrict__ h1init)
{
  const int stride = gridDim.x * 256;
  for (int idx = blockIdx.x * 256 + threadIdx.x; idx < S4E; idx += stride) {
    if (idx < S0E) {
      int r = idx >> 9, c = idx & 511;
      embf16[idx] = (f16)(r < VOC ? emb[(size_t)r * 512 + c] : 0.f);
    } else if (idx < S1E) {
      int i = idx - S0E;
      int r = i >> 9, c = i & 511;
      woutf16[i] = (f16)(r < VOC ? Wout[(size_t)r * 512 + c] : 0.f);
    } else if (idx < S2E) {
      int i = idx - S1E;
      int r = i >> 9, c = i & 511;
      w0xf16[i] = (f16)W0[(size_t)r * 1024 + c];
    } else if (idx < S3E) {
      int i = idx - S2E;
      h0init[i] = (f16)hidden[i];
    } else {
      int i = idx - S3E;
      h1init[i] = (f16)hidden[B_SZ * HIDN + i];
    }
  }
}

// ---- GEMM: C[M][ldc] = A[*][512] . B[*][512]^T + bias[col]; 256x128 tiles ----
// 512 threads (8 waves: wrow in [0,4) x wcol in [0,2)), single-buffered BK=32,
// 24 KB LDS (TLP hides stage latency — R13/R15 lesson; R16 showed 256x256's
// register pressure crosses the 2-waves/SIMD cliff, 256x128 is the sweet spot).
// All fragment math byte-identical to the proven R8 kernel (chunk-linear LDS,
// sp^((row>>1)&3) swizzle, swapped-operand MFMA, dwordx4 C-stores).
template <typename CT>
__global__ __launch_bounds__(512) void gemm_k512(
    const f16* __restrict__ A, const f16* __restrict__ B,
    CT* __restrict__ C, const float* __restrict__ bias,
    int M, int N, int ldc)
{
  __shared__ f16 Asw[256 * 32];   // 16 KB
  __shared__ f16 Bsw[128 * 32];   //  8 KB
  const int tid  = threadIdx.x;
  const int lane = tid & 63, w = tid >> 6;     // w in [0,8)
  const int wrow = w >> 1, wcol = w & 1;
  int nwg  = gridDim.x * gridDim.y;
  int orig = blockIdx.y * gridDim.x + blockIdx.x;
  int cpx  = nwg >> 3;
  int swz  = (orig & 7) * cpx + (orig >> 3);
  const int m0 = (swz / gridDim.x) * 256, n0 = (swz % gridDim.x) * 128;
  const int rsel = lane & 15, ksl = lane >> 4;

  f32x4 acc[4][4] = {};

  for (int kt = 0; kt < 16; ++kt) {
    __syncthreads();   // previous tile's readers done -> safe to overwrite
    // A-tile: 1024 16B-chunks; wave w stages wavechunks {w, w+8}
#pragma unroll
    for (int i = 0; i < 2; ++i) {
      int ac  = i * 8 + w;
      int c   = ac * 64 + lane;
      int row = c >> 2, sp = c & 3;
      int sl  = sp ^ ((row >> 1) & 3);         // source pre-swizzle
      gload_lds16(A + (size_t)(m0 + row) * 512 + kt * 32 + sl * 8,
                  &Asw[ac * 512]);             // wave-uniform base + lane*16
    }
    // B-tile: 512 chunks; wave w stages wavechunk w
    {
      int c   = w * 64 + lane;
      int row = c >> 2, sp = c & 3;
      int sl  = sp ^ ((row >> 1) & 3);
      gload_lds16(B + (size_t)(n0 + row) * 512 + kt * 32 + sl * 8,
                  &Bsw[w * 512]);
    }
    __syncthreads();   // implicit vmcnt(0) drain -> staged tile visible

    f16x8 af[4], bf[4];
#pragma unroll
    for (int i = 0; i < 4; ++i) {
      int ar = wrow * 64 + i * 16 + rsel;
      af[i] = *(const f16x8*)&Asw[ar * 32 + ((ksl ^ ((ar >> 1) & 3)) * 8)];
      int br = wcol * 64 + i * 16 + rsel;
      bf[i] = *(const f16x8*)&Bsw[br * 32 + ((ksl ^ ((br >> 1) & 3)) * 8)];
    }
    // swapped operands: acc[i][j] = C[m0+wrow*64+i*16+rsel][n0+wcol*64+j*16+ksl*4 ..+3]
#pragma unroll
    for (int i = 0; i < 4; ++i)
#pragma unroll
      for (int j = 0; j < 4; ++j)
        acc[i][j] = __builtin_amdgcn_mfma_f32_16x16x32_f16(bf[j], af[i], acc[i][j], 0, 0, 0);
  }

#pragma unroll
  for (int i = 0; i < 4; ++i) {
    int row = m0 + wrow * 64 + i * 16 + rsel;
    if (row >= M) continue;
#pragma unroll
    for (int j = 0; j < 4; ++j) {
      int nb = n0 + wcol * 64 + j * 16 + ksl * 4;
      if (nb >= N) continue;        // N % 4 == 0 => whole quad in/out together
      f32x4 v = acc[i][j];
      if (bias) {
        f32x4 bv = *(const f32x4*)(bias + nb);
        v += bv;
      }
      if constexpr (__is_same(CT, float)) {
        *(f32x4*)&C[(size_t)row * ldc + nb] = v;
      } else {
        f16x4 hv;
#pragma unroll
        for (int q = 0; q < 4; ++q) hv[q] = (f16)v[q];
        *(f16x4*)&C[(size_t)row * ldc + nb] = hv;
      }
    }
  }
}

// ---- cooperative recurrence: R13-EXACT (proven passing; frozen) ----
// R12 race-free MAIN + batch-group-local flags. Block (cgI,bg) reads/writes
// h0ring & H1 rows in [bg*64,(bg+1)*64) only => each bg's 128 wave-flags form
// an independent barrier. Bound: 8 MB/phase sc1 traffic / ~1.4 TB/s ≈ 5.8 µs/phase.
__global__ __launch_bounds__(256, 1) void rnn_recur(
    const int* __restrict__ tok,    // [128][128]
    const float* __restrict__ W0,   // [512][1024]
    const float* __restrict__ W1,   // [512][1024]
    const float* __restrict__ b1,   // [512]
    const f16* __restrict__ P0h,    // [10000][512]  emb@W0x^T + b0
    f16* __restrict__ h0ring,       // [4][128][512] (slot 3 = initial h0)
    const f16* __restrict__ h1init, // [128][512]
    f16* __restrict__ H1,           // [128][128][512]
    float* __restrict__ outHid,     // [2][128][512] (d_out tail)
    unsigned* __restrict__ flags)   // [2][128] per-wave flags (zeroed each launch)
{
  __shared__ f16 wlds[3][16 * 512];   // W0h^T, W1a^T, W1b^T column slices, XOR-swizzled
  const int tid = threadIdx.x;
  const int lane = tid & 63, w = tid >> 6;
  const int cgI = blockIdx.x & 31, bg = blockIdx.x >> 5;
  const int col0 = cgI * 16;
  const int rowstart = bg * 64 + w * 16;
  const int rsel = lane & 15, ksl = lane >> 4;
  unsigned* gflags = flags + bg * 128;
  const int fidx = cgI * 4 + w;

  for (int it = tid; it < 3 * 16 * 64; it += 256) {
    int s = it >> 10;
    int rem = it & 1023;
    int c = rem >> 6, ks = rem & 63;
    int n = col0 + c;
    const float* srcp;
    if (s == 0)      srcp = W0 + (size_t)n * 1024 + 512 + ks * 8;  // W0h
    else if (s == 1) srcp = W1 + (size_t)n * 1024 + ks * 8;        // W1a
    else             srcp = W1 + (size_t)n * 1024 + 512 + ks * 8;  // W1b
    f16x8 v;
#pragma unroll
    for (int j = 0; j < 8; ++j) v[j] = (f16)srcp[j];
    *(f16x8*)&wlds[s][c * 512 + ((ks ^ (c & 7)) * 8)] = v;
  }
  const f32x4 b1q = *(const f32x4*)(b1 + col0 + ksl * 4);
  __syncthreads();   // weights visible to all waves; after this, waves are autonomous

  const int myrow = rowstart + rsel;          // lane's batch row
  const size_t hrow = (size_t)myrow * HIDN;
  const int colq = col0 + ksl * 4;            // lane's 4 consecutive hidden cols
  const unsigned* fptr = gflags + 2 * lane;   // 64 lanes x 2 = own bg's 128 flags

  f16x8 hf[16];   // h0(p-1) after MAIN(p); h0(p-2) during SHADOW(p)
  f32x4 part1;

  for (int p = 0; p <= S_LEN + 1; ++p) {
    const bool doH0 = (p <= S_LEN - 1);
    const bool doH1 = (p >= 2);

    // ---- SHADOW: part1 = b1 + W1a@h0(p-2) [regs]; gather (pinned) ----
    if (doH1) {
      f32x4 t = b1q;
#pragma unroll
      for (int kt = 0; kt < 16; ++kt) {
        int ks = kt * 4 + ksl;
        f16x8 b = *(const f16x8*)&wlds[1][rsel * 512 + ((ks ^ (rsel & 7)) * 8)];
        t = __builtin_amdgcn_mfma_f32_16x16x32_f16(b, hf[kt], t, 0, 0, 0);
      }
      part1 = t;
    }
    float pa0, pa1, pa2, pa3;
    if (doH0) {
      int t_ = tok[p * B_SZ + myrow];
      f16x4 pv = *(const f16x4*)&P0h[(size_t)t_ * HIDN + colq];
      pa0 = (float)pv[0]; pa1 = (float)pv[1]; pa2 = (float)pv[2]; pa3 = (float)pv[3];
      // pin: force gather completion here so compiler waitcnts stay out of MAIN
      asm volatile("" : "+v"(pa0), "+v"(pa1), "+v"(pa2), "+v"(pa3));
    }

    // ---- WAIT: own bg's 128 wave-flags >= p ----
    if (p >= 1) {
      const unsigned tgt = (unsigned)p;
      for (;;) {
        u32x2 f;
        asm volatile("global_load_dwordx2 %0, %1, off sc1\n\ts_waitcnt vmcnt(0)"
                     : "=v"(f) : "v"(fptr) : "memory");
        int ok = (f[0] >= tgt) & (f[1] >= tgt);
        if (__all(ok)) break;
      }
    }

    // ---- MAIN: issue device-scope loads (hf first: critical path) ----
    if (p <= S_LEN) {
      const f16* src = h0ring + (size_t)((p - 1) & 3) * B_SZ * HIDN;
#pragma unroll
      for (int kt = 0; kt < 16; ++kt)
        hf[kt] = ld16_dev(src + hrow + kt * 32 + ksl * 8);
    }
    f16x8 h1f[16];
    if (doH1) {
      const f16* h1src = (p == 2) ? h1init : H1 + (size_t)(p - 3) * B_SZ * HIDN;
#pragma unroll
      for (int kt = 0; kt < 16; ++kt)
        h1f[kt] = ld16_dev(h1src + hrow + kt * 32 + ksl * 8);
    }

    float v0, v1, v2, v3;           // layer-0 activations
    if (doH0) {
      if (doH1) { VMCNT(16); } else { VMCNT(0); }   // hf (oldest 16) retired
      f32x4 acc0 = {pa0, pa1, pa2, pa3};
#pragma unroll
      for (int kt = 0; kt < 16; ++kt) {
        int ks = kt * 4 + ksl;
        f16x8 b = *(const f16x8*)&wlds[0][rsel * 512 + ((ks ^ (rsel & 7)) * 8)];
        acc0 = __builtin_amdgcn_mfma_f32_16x16x32_f16(b, hf[kt], acc0, 0, 0, 0);
      }
      v0 = fast_tanh(acc0[0]); v1 = fast_tanh(acc0[1]);
      v2 = fast_tanh(acc0[2]); v3 = fast_tanh(acc0[3]);
      f16* dst = h0ring + (size_t)(p & 3) * B_SZ * HIDN;
      f16x4 hv = {(f16)v0, (f16)v1, (f16)v2, (f16)v3};
      cstore8(&dst[hrow + colq], hv);           // exactly 1 store in flight
    }
    if (doH1) {
      if (doH0) { VMCNT(1); } else { VMCNT(0); }
      // vmcnt in-order: <=1 outstanding => all 16 h1f retired; h0 store may fly
      f32x4 acc1 = part1;
#pragma unroll
      for (int kt = 0; kt < 16; ++kt) {
        int ks = kt * 4 + ksl;
        f16x8 b = *(const f16x8*)&wlds[2][rsel * 512 + ((ks ^ (rsel & 7)) * 8)];
        acc1 = __builtin_amdgcn_mfma_f32_16x16x32_f16(b, h1f[kt], acc1, 0, 0, 0);
      }
      float u0 = fast_tanh(acc1[0]), u1 = fast_tanh(acc1[1]);
      float u2 = fast_tanh(acc1[2]), u3 = fast_tanh(acc1[3]);
      f16* h1dst = H1 + (size_t)(p - 2) * B_SZ * HIDN;
      f16x4 hv = {(f16)u0, (f16)u1, (f16)u2, (f16)u3};
      cstore8(&h1dst[hrow + colq], hv);
      if (p == S_LEN + 1) {
        f32x4 fv = {u0, u1, u2, u3};
        *(f32x4*)&outHid[(size_t)(B_SZ * HIDN) + hrow + colq] = fv;
      }
    }
    if (doH0 && p == S_LEN - 1) {   // deferred (rare): keeps the VMCNT(1) count exact
      f32x4 fv = {v0, v1, v2, v3};
      *(f32x4*)&outHid[hrow + colq] = fv;
    }

    // ---- ARRIVE: per-wave drain + own-flag store ----
    if (p <= S_LEN) {
      VMCNT(0);
      if (lane == 0) stflag_dev(gflags + fidx, (unsigned)(p + 1));
    }
  }
}

extern "C" void kernel_launch(void* const* d_in, const int* in_sizes, int n_in,
                              void* d_out, int out_size, void* d_ws, size_t ws_size,
                              hipStream_t stream) {
  (void)in_sizes; (void)n_in; (void)out_size; (void)ws_size;
  const int*   tok    = (const int*)d_in[0];
  const float* hidden = (const float*)d_in[1];
  const float* emb    = (const float*)d_in[2];
  const float* W0     = (const float*)d_in[3];
  const float* b0     = (const float*)d_in[4];
  const float* W1     = (const float*)d_in[5];
  const float* b1     = (const float*)d_in[6];
  const float* Wout   = (const float*)d_in[7];
  const float* bout   = (const float*)d_in[8];

  char* ws = (char*)d_ws;
  size_t off = 0;
  f16* embf16  = (f16*)(ws + off); off += (size_t)VPAD * 512 * 2;
  f16* woutf16 = (f16*)(ws + off); off += (size_t)VPAD * 512 * 2;
  f16* w0xf16  = (f16*)(ws + off); off += (size_t)512 * 512 * 2;
  f16* P0h     = (f16*)(ws + off); off += (size_t)VOC * 512 * 2;
  f16* H1      = (f16*)(ws + off); off += (size_t)S_LEN * B_SZ * 512 * 2;
  f16* h0ring  = (f16*)(ws + off); off += (size_t)4 * B_SZ * 512 * 2;
  f16* h1init  = (f16*)(ws + off); off += (size_t)B_SZ * 512 * 2;
  unsigned* flags = (unsigned*)(ws + off); off += NFLAG * 4;

  float* outHid = (float*)d_out + (size_t)S_LEN * B_SZ * VOC;

  hipMemsetAsync(flags, 0, NFLAG * 4, stream);   // reset flags each launch

  // all fp32->f16 staging in one grid-stride launch (was 5 launch-bound kernels)
  convert_all<<<2048, 256, 0, stream>>>(
      emb, Wout, W0, hidden, embf16, woutf16, w0xf16,
      h0ring + (size_t)3 * B_SZ * 512, h1init);

  // P0 = emb @ W0x^T + b0  (f16 out, [10000][512]); 256-row tiles: 40 x 4 grid
  gemm_k512<f16><<<dim3(4, VPAD / 256), 512, 0, stream>>>(
      embf16, w0xf16, P0h, b0, VOC, 512, 512);

  // recurrence (cooperative for co-residency; bg-local wave-flag sync inside)
  {
    void* args[] = {(void*)&tok, (void*)&W0, (void*)&W1, (void*)&b1, (void*)&P0h,
                    (void*)&h0ring, (void*)&h1init, (void*)&H1, (void*)&outHid, (void*)&flags};
    hipLaunchCooperativeKernel((const void*)rnn_recur, dim3(NBLK), dim3(256), args, 0, stream);
  }

  // logits = H1 @ Wout^T + bout  -> d_out [16384][10000] fp32; 256x128 tiles
  gemm_k512<float><<<dim3(79, 64), 512, 0, stream>>>(
      H1, woutf16, (float*)d_out, bout, S_LEN * B_SZ, VOC, VOC);
}